// Round 7
// baseline (331.857 us; speedup 1.0000x reference)
//
#include <hip/hip_runtime.h>
#include <math.h>

// Problem constants: N=50000, E=800000, D=H=64, ED=16.
// Pipeline (CSR gather, bf16 g, atomic-free fill, in-kernel weight packing):
//   cnt[i]=indeg, rank[e]=arrival order  (hist — atomicAdd return IS the rank)
//   row_start = exscan(cnt); dinv = rsqrt(cnt+1)   (scan1/2/3)
//   csr[row_start[dst]+rank] = src                 (fill, NO atomics)
//   gbf = bf16((x @ W1) * dinv[row])               (node_gemm_mfma, packs W1 in-kernel)
//   hbf[i] = bf16(relu(dinv[i]*(gbf[i] + sum gbf[s]) + b1))  (gather_finalize)
//   out[e] = sigmoid(relu([h_s|h_d|ea]@Wm1+bm1)@Wm2+bm2)     (edge_mlp_mfma)
//
// NOTES:
//  - hbf must NOT alias gbf (gather reads arbitrary neighbor rows while writing hbf).
//  - edge_mlp: 16 edges/wave, A-frags prefetched into af[5] with a sched_barrier
//    between load and MFMA phases — R5 showed compiler reuses frag registers
//    (VGPR 32) serializing the gathers; grid-stride persistent waves regressed.

typedef __attribute__((ext_vector_type(8))) short bf16x8;
typedef __attribute__((ext_vector_type(4))) float f32x4;

__device__ __forceinline__ unsigned short f2b(float f) {
    unsigned u = __float_as_uint(f);
    unsigned r = (u + 0x7FFFu + ((u >> 16) & 1u)) >> 16;   // RNE
    return (unsigned short)r;
}

__global__ void hist(const int* __restrict__ dst, int* __restrict__ cnt,
                     int* __restrict__ rank, int E) {
    int e = blockIdx.x * blockDim.x + threadIdx.x;
    if (e < E) rank[e] = atomicAdd(&cnt[dst[e]], 1);
}

__global__ void scan1(const int* __restrict__ cnt, int* __restrict__ part,
                      int* __restrict__ bsum, int N) {
    __shared__ int s[256];
    int tid = threadIdx.x;
    int i = blockIdx.x * 256 + tid;
    int v = (i < N) ? cnt[i] : 0;
    s[tid] = v;
    __syncthreads();
#pragma unroll
    for (int off = 1; off < 256; off <<= 1) {
        int t = (tid >= off) ? s[tid - off] : 0;
        __syncthreads();
        s[tid] += t;
        __syncthreads();
    }
    if (i < N) part[i] = s[tid] - v;
    if (tid == 255) bsum[blockIdx.x] = s[255];
}

__global__ void scan2(int* __restrict__ bsum, int nb) {
    __shared__ int s[256];
    int tid = threadIdx.x;
    int v = (tid < nb) ? bsum[tid] : 0;
    s[tid] = v;
    __syncthreads();
#pragma unroll
    for (int off = 1; off < 256; off <<= 1) {
        int t = (tid >= off) ? s[tid - off] : 0;
        __syncthreads();
        s[tid] += t;
        __syncthreads();
    }
    if (tid < nb) bsum[tid] = s[tid] - v;
}

__global__ void scan3(int* __restrict__ row_start, const int* __restrict__ bsum,
                      const int* __restrict__ cnt, float* __restrict__ dinv, int N) {
    int i = blockIdx.x * 256 + threadIdx.x;
    if (i >= N) return;
    int rs = row_start[i] + bsum[blockIdx.x];
    row_start[i] = rs;
    dinv[i] = rsqrtf((float)cnt[i] + 1.0f);
    if (i == N - 1) row_start[N] = rs + cnt[i];
}

// atomic-free: unique slot = row_start[dst] + rank
__global__ void fill(const int* __restrict__ src, const int* __restrict__ dst,
                     const int* __restrict__ rank, const int* __restrict__ row_start,
                     int* __restrict__ csr, int E) {
    int e = blockIdx.x * blockDim.x + threadIdx.x;
    if (e >= E) return;
    csr[row_start[dst[e]] + rank[e]] = src[e];
}

// B-frag layout for mfma_f32_16x16x32_bf16, W is [K x 64] row-major, K-steps of 32:
//   sB[((s*4+t)*64 + lane)*8 + j] = W[s*32 + (lane>>4)*8 + j][t*16 + (lane&15)]
__device__ __forceinline__ void pack_lds(const float* __restrict__ W, int K, int ksteps,
                                         unsigned short* __restrict__ sB) {
    int total = ksteps * 4 * 64 * 8;
    for (int idx = threadIdx.x; idx < total; idx += 256) {
        int j = idx & 7, lane = (idx >> 3) & 63, t = (idx >> 9) & 3, s = idx >> 11;
        int k = s * 32 + ((lane >> 4) << 3) + j, col = (t << 4) + (lane & 15);
        sB[idx] = (k < K) ? f2b(W[k * 64 + col]) : 0;
    }
}

__global__ void __launch_bounds__(256) node_gemm_mfma(
        const float* __restrict__ x, const float* __restrict__ W1,
        const float* __restrict__ dinv, unsigned short* __restrict__ gbf, int NW) {
    __shared__ unsigned short sB[2 * 4 * 64 * 8];   // 8 KB
    pack_lds(W1, 64, 2, sB);
    __syncthreads();
    int wid = blockIdx.x * 4 + (threadIdx.x >> 6);
    if (wid >= NW) return;
    int lane = threadIdx.x & 63, m = lane & 15, quad = lane >> 4;
    int r0 = wid * 16;
    f32x4 acc[4];
#pragma unroll
    for (int t = 0; t < 4; ++t) acc[t] = (f32x4){0.f, 0.f, 0.f, 0.f};
    const bf16x8* bp = (const bf16x8*)sB;
#pragma unroll
    for (int s = 0; s < 2; ++s) {
        const float4* xp = (const float4*)(x + (size_t)(r0 + m) * 64 + s * 32 + quad * 8);
        float4 v0 = xp[0], v1 = xp[1];
        bf16x8 a;
        a[0] = (short)f2b(v0.x); a[1] = (short)f2b(v0.y);
        a[2] = (short)f2b(v0.z); a[3] = (short)f2b(v0.w);
        a[4] = (short)f2b(v1.x); a[5] = (short)f2b(v1.y);
        a[6] = (short)f2b(v1.z); a[7] = (short)f2b(v1.w);
#pragma unroll
        for (int t = 0; t < 4; ++t)
            acc[t] = __builtin_amdgcn_mfma_f32_16x16x32_bf16(
                a, bp[(s * 4 + t) * 64 + lane], acc[t], 0, 0, 0);
    }
#pragma unroll
    for (int reg = 0; reg < 4; ++reg) {
        int row = r0 + quad * 4 + reg;
        float di = dinv[row];
#pragma unroll
        for (int t = 0; t < 4; ++t)
            gbf[(size_t)row * 64 + t * 16 + m] = f2b(acc[t][reg] * di);
    }
}

// wave per node; 2 neighbors per step (lane>>5 = neighbor parity, lane&31 = col pair);
// unrolled 8 pairs deep to keep 8 gather loads in flight.
__global__ void __launch_bounds__(256) gather_finalize(
        const unsigned int* __restrict__ gbf_u, const int* __restrict__ csr,
        const int* __restrict__ row_start, const float* __restrict__ dinv,
        const float* __restrict__ b1, unsigned int* __restrict__ hbf_u, int N) {
    int wid = blockIdx.x * 4 + (threadIdx.x >> 6);
    if (wid >= N) return;
    int lane = threadIdx.x & 63;
    int which = lane >> 5, c2 = lane & 31;
    int base = row_start[wid];
    int deg = row_start[wid + 1] - base;
    float a0 = 0.f, a1 = 0.f;
    if (which == 0) {   // self loop row
        unsigned u = gbf_u[(size_t)wid * 32 + c2];
        a0 += __uint_as_float(u << 16);
        a1 += __uint_as_float(u & 0xffff0000u);
    }
    for (int j0 = 0; j0 < deg; j0 += 64) {
        int nidx = j0 + lane;
        int sidx = (nidx < deg) ? csr[base + nidx] : 0;
        int cnt = deg - j0; if (cnt > 64) cnt = 64;
        int full = cnt >> 1;
        int p = 0;
        for (; p + 8 <= full; p += 8) {
            unsigned u[8];
#pragma unroll
            for (int q = 0; q < 8; ++q) {
                int n = __shfl(sidx, (p + q) * 2 + which, 64);
                u[q] = gbf_u[(size_t)n * 32 + c2];
            }
#pragma unroll
            for (int q = 0; q < 8; ++q) {
                a0 += __uint_as_float(u[q] << 16);
                a1 += __uint_as_float(u[q] & 0xffff0000u);
            }
        }
        for (; p + 4 <= full; p += 4) {
            unsigned u[4];
#pragma unroll
            for (int q = 0; q < 4; ++q) {
                int n = __shfl(sidx, (p + q) * 2 + which, 64);
                u[q] = gbf_u[(size_t)n * 32 + c2];
            }
#pragma unroll
            for (int q = 0; q < 4; ++q) {
                a0 += __uint_as_float(u[q] << 16);
                a1 += __uint_as_float(u[q] & 0xffff0000u);
            }
        }
        for (; p < full; ++p) {
            int n = __shfl(sidx, p * 2 + which, 64);
            unsigned u = gbf_u[(size_t)n * 32 + c2];
            a0 += __uint_as_float(u << 16);
            a1 += __uint_as_float(u & 0xffff0000u);
        }
        if (cnt & 1) {
            int n = __shfl(sidx, cnt - 1, 64);
            if (which == 0) {
                unsigned u = gbf_u[(size_t)n * 32 + c2];
                a0 += __uint_as_float(u << 16);
                a1 += __uint_as_float(u & 0xffff0000u);
            }
        }
    }
    a0 += __shfl_xor(a0, 32, 64);
    a1 += __shfl_xor(a1, 32, 64);
    if (which == 0) {
        float di = dinv[wid];
        float h0 = di * a0 + b1[2 * c2];
        float h1 = di * a1 + b1[2 * c2 + 1];
        h0 = h0 > 0.f ? h0 : 0.f;
        h1 = h1 > 0.f ? h1 : 0.f;
        hbf_u[(size_t)wid * 32 + c2] = (unsigned)f2b(h0) | ((unsigned)f2b(h1) << 16);
    }
}

// One wave per 16 edges; K=160 (144 padded), 4 N-tiles. All 5 A-frags loaded
// BEFORE the MFMA phase (sched_barrier keeps the phases separate).
__global__ void __launch_bounds__(256, 8) edge_mlp_mfma(
        const unsigned short* __restrict__ hbf, const float* __restrict__ ea,
        const int* __restrict__ src, const int* __restrict__ dst,
        const float* __restrict__ Wm1,
        const float* __restrict__ bm1, const float* __restrict__ Wm2,
        const float* __restrict__ bm2, float* __restrict__ out, int E) {
    __shared__ unsigned short sB[5 * 4 * 64 * 8];   // 20 KB
    pack_lds(Wm1, 144, 5, sB);
    __syncthreads();

    int lane = threadIdx.x & 63;
    int wave = threadIdx.x >> 6;
    int m = lane & 15, quad = lane >> 4;
    int e0 = (blockIdx.x * 4 + wave) * 16;
    if (e0 >= E) return;
    int e = e0 + m;
    int ec = e < E ? e : E - 1;
    int si = src[ec], di = dst[ec];

    // ---- load phase: all gathers in flight ----
    bf16x8 af[5];
    af[0] = *(const bf16x8*)(hbf + (size_t)si * 64 + quad * 8);
    af[1] = *(const bf16x8*)(hbf + (size_t)si * 64 + 32 + quad * 8);
    af[2] = *(const bf16x8*)(hbf + (size_t)di * 64 + quad * 8);
    af[3] = *(const bf16x8*)(hbf + (size_t)di * 64 + 32 + quad * 8);
    if (quad < 2) {
        const float4* ep = (const float4*)(ea + (size_t)ec * 16 + quad * 8);
        float4 v0 = ep[0], v1 = ep[1];
        af[4][0] = (short)f2b(v0.x); af[4][1] = (short)f2b(v0.y);
        af[4][2] = (short)f2b(v0.z); af[4][3] = (short)f2b(v0.w);
        af[4][4] = (short)f2b(v1.x); af[4][5] = (short)f2b(v1.y);
        af[4][6] = (short)f2b(v1.z); af[4][7] = (short)f2b(v1.w);
    } else {
#pragma unroll
        for (int j = 0; j < 8; ++j) af[4][j] = 0;
    }
    __builtin_amdgcn_sched_barrier(0);

    // ---- MFMA phase ----
    f32x4 acc[4];
#pragma unroll
    for (int t = 0; t < 4; ++t) acc[t] = (f32x4){0.f, 0.f, 0.f, 0.f};
    const bf16x8* bp = (const bf16x8*)sB;
#pragma unroll
    for (int s = 0; s < 5; ++s) {
#pragma unroll
        for (int t = 0; t < 4; ++t)
            acc[t] = __builtin_amdgcn_mfma_f32_16x16x32_bf16(
                af[s], bp[(s * 4 + t) * 64 + lane], acc[t], 0, 0, 0);
    }

    // epilogue: +bm1, relu, dot Wm2, reduce over 16 col-lanes, sigmoid
    float w2[4], bb[4];
#pragma unroll
    for (int t = 0; t < 4; ++t) {
        int col = t * 16 + m;
        bb[t] = bm1[col];
        w2[t] = Wm2[col];
    }
    float p[4];
#pragma unroll
    for (int r = 0; r < 4; ++r) {
        float sum = 0.0f;
#pragma unroll
        for (int t = 0; t < 4; ++t) {
            float hv = acc[t][r] + bb[t];
            sum += (hv > 0.0f ? hv : 0.0f) * w2[t];
        }
        p[r] = sum;
    }
#pragma unroll
    for (int off = 1; off < 16; off <<= 1) {
#pragma unroll
        for (int r = 0; r < 4; ++r) p[r] += __shfl_xor(p[r], off, 64);
    }
    float b2 = bm2[0];
    if (m < 4) {
        int eo = e0 + quad * 4 + m;
        if (eo < E) out[eo] = 1.0f / (1.0f + __expf(-(p[m] + b2)));
    }
}

extern "C" void kernel_launch(void* const* d_in, const int* in_sizes, int n_in,
                              void* d_out, int out_size, void* d_ws, size_t ws_size,
                              hipStream_t stream) {
    const float* x   = (const float*)d_in[0];
    const int*   src = (const int*)d_in[1];
    const int*   dst = (const int*)d_in[2];
    const float* ea  = (const float*)d_in[3];
    const float* W1  = (const float*)d_in[4];
    const float* b1  = (const float*)d_in[5];
    const float* Wm1 = (const float*)d_in[6];
    const float* bm1 = (const float*)d_in[7];
    const float* Wm2 = (const float*)d_in[8];
    const float* bm2 = (const float*)d_in[9];
    float* out = (float*)d_out;

    const int N = in_sizes[0] / 64;   // 50000
    const int E = in_sizes[1];        // 800000
    const int NB = (N + 255) / 256;   // 196
    const int NW = N / 16;            // 3125

    // ws layout (all chunks 256B-aligned):
    unsigned short* gbf = (unsigned short*)d_ws;            // N*64 bf16 (6.4 MB)
    unsigned short* hbf = gbf + (size_t)N * 64;             // N*64 bf16 (6.4 MB)
    int*   csr       = (int*)(hbf + (size_t)N * 64);        // E  (3.2 MB)
    int*   rank      = csr + E;                             // E  (3.2 MB)
    int*   cnt       = rank + E;                            // N
    int*   row_start = cnt + N;                             // N+1
    int*   bsum      = row_start + N + 2;                   // 256
    float* dinv      = (float*)(bsum + 256);                // N

    hipMemsetAsync(cnt, 0, (size_t)N * sizeof(int), stream);
    hist<<<(E + 255) / 256, 256, 0, stream>>>(dst, cnt, rank, E);
    scan1<<<NB, 256, 0, stream>>>(cnt, row_start, bsum, N);
    scan2<<<1, 256, 0, stream>>>(bsum, NB);
    scan3<<<NB, 256, 0, stream>>>(row_start, bsum, cnt, dinv, N);
    fill<<<(E + 255) / 256, 256, 0, stream>>>(src, dst, rank, row_start, csr, E);
    node_gemm_mfma<<<(NW + 3) / 4, 256, 0, stream>>>(x, W1, dinv, gbf, NW);
    gather_finalize<<<(N + 3) / 4, 256, 0, stream>>>((const unsigned int*)gbf, csr,
                                                     row_start, dinv, b1,
                                                     (unsigned int*)hbf, N);
    edge_mlp_mfma<<<(E + 63) / 64, 256, 0, stream>>>(hbf, ea, src, dst, Wm1,
                                                     bm1, Wm2, bm2, out, E);
}

// Round 8
// 232.048 us; speedup vs baseline: 1.4301x; 1.4301x over previous
//
#include <hip/hip_runtime.h>
#include <math.h>

// Problem constants: N=50000, E=800000, D=H=64, ED=16.
// Pipeline (CSR gather, bf16 g, atomic-free fill, PRE-PACKED weights):
//   cnt[i]=indeg, rank[e]=arrival order  (hist — atomicAdd return IS the rank)
//   row_start = exscan(cnt); dinv = rsqrt(cnt+1)   (scan1 + scan23)
//   csr[row_start[dst]+rank] = src                 (fill, NO atomics)
//   gbf = bf16((x @ W1) * dinv[row])               (node_gemm_mfma)
//   hbf[i] = bf16(relu(dinv[i]*(gbf[i] + sum gbf[s]) + b1))  (gather_finalize)
//   out[e] = sigmoid(relu([h_s|h_d|ea]@Wm1+bm1)@Wm2+bm2)     (edge_mlp_mfma)
//
// LESSONS ENCODED:
//  - hbf must NOT alias gbf (cross-block RW race).
//  - Weight packing must be a separate tiny kernel (Bp/Bp1) + int4 LDS staging;
//    in-kernel pack_lds was 10k scalar loads/block and tripled edge_mlp (R6).
//  - edge_mlp: 16 edges/wave; grid-stride persistent waves regressed (R5).

typedef __attribute__((ext_vector_type(8))) short bf16x8;
typedef __attribute__((ext_vector_type(4))) float f32x4;

__device__ __forceinline__ unsigned short f2b(float f) {
    unsigned u = __float_as_uint(f);
    unsigned r = (u + 0x7FFFu + ((u >> 16) & 1u)) >> 16;   // RNE
    return (unsigned short)r;
}

__global__ void hist(const int* __restrict__ dst, int* __restrict__ cnt,
                     int* __restrict__ rank, int E) {
    int e = blockIdx.x * blockDim.x + threadIdx.x;
    if (e < E) rank[e] = atomicAdd(&cnt[dst[e]], 1);
}

__global__ void scan1(const int* __restrict__ cnt, int* __restrict__ part,
                      int* __restrict__ bsum, int N) {
    __shared__ int s[256];
    int tid = threadIdx.x;
    int i = blockIdx.x * 256 + tid;
    int v = (i < N) ? cnt[i] : 0;
    s[tid] = v;
    __syncthreads();
#pragma unroll
    for (int off = 1; off < 256; off <<= 1) {
        int t = (tid >= off) ? s[tid - off] : 0;
        __syncthreads();
        s[tid] += t;
        __syncthreads();
    }
    if (i < N) part[i] = s[tid] - v;
    if (tid == 255) bsum[blockIdx.x] = s[255];
}

// scan2+scan3 fused: every block redundantly scans bsum (nb<=256) in LDS and
// takes its own exclusive offset; then finalizes row_start/dinv.
__global__ void scan23(int* __restrict__ row_start, const int* __restrict__ bsum,
                       const int* __restrict__ cnt, float* __restrict__ dinv,
                       int N, int nb) {
    __shared__ int s[256];
    int tid = threadIdx.x;
    int v = (tid < nb) ? bsum[tid] : 0;
    s[tid] = v;
    __syncthreads();
#pragma unroll
    for (int off = 1; off < 256; off <<= 1) {
        int t = (tid >= off) ? s[tid - off] : 0;
        __syncthreads();
        s[tid] += t;
        __syncthreads();
    }
    int blkoff = (blockIdx.x > 0) ? s[blockIdx.x - 1] : 0;   // exclusive prefix
    int i = blockIdx.x * 256 + tid;
    if (i >= N) return;
    int rs = row_start[i] + blkoff;
    row_start[i] = rs;
    dinv[i] = rsqrtf((float)cnt[i] + 1.0f);
    if (i == N - 1) row_start[N] = rs + cnt[i];
}

// atomic-free: unique slot = row_start[dst] + rank
__global__ void fill(const int* __restrict__ src, const int* __restrict__ dst,
                     const int* __restrict__ rank, const int* __restrict__ row_start,
                     int* __restrict__ csr, int E) {
    int e = blockIdx.x * blockDim.x + threadIdx.x;
    if (e >= E) return;
    csr[row_start[dst[e]] + rank[e]] = src[e];
}

// Pack Wm1 [144x64] -> Bp (5 K-steps, K padded 160) and W1 [64x64] -> Bp1 (2 K-steps)
// in mfma_f32_16x16x32_bf16 B-fragment layout:
//   Bx[((s*4+t)*64 + lane)*8 + j] = W[s*32 + (lane>>4)*8 + j][t*16 + (lane&15)]
__global__ void pack_B(const float* __restrict__ Wm1, const float* __restrict__ W1,
                       unsigned short* __restrict__ Bp, unsigned short* __restrict__ Bp1) {
    int idx = blockIdx.x * blockDim.x + threadIdx.x;
    if (idx < 5 * 4 * 64 * 8) {
        int j = idx & 7, lane = (idx >> 3) & 63, t = (idx >> 9) & 3, s = idx >> 11;
        int k = s * 32 + (lane >> 4) * 8 + j, col = t * 16 + (lane & 15);
        float v = (k < 144) ? Wm1[k * 64 + col] : 0.0f;
        Bp[idx] = f2b(v);
    } else {
        int idx2 = idx - 5 * 4 * 64 * 8;
        if (idx2 < 2 * 4 * 64 * 8) {
            int j = idx2 & 7, lane = (idx2 >> 3) & 63, t = (idx2 >> 9) & 3, s = idx2 >> 11;
            int k = s * 32 + (lane >> 4) * 8 + j, col = t * 16 + (lane & 15);
            Bp1[idx2] = f2b(W1[k * 64 + col]);
        }
    }
}

__global__ void __launch_bounds__(256) node_gemm_mfma(
        const float* __restrict__ x, const unsigned short* __restrict__ Bp1,
        const float* __restrict__ dinv, unsigned short* __restrict__ gbf, int NW) {
    __shared__ unsigned short sB[2 * 4 * 64 * 8];   // 8 KB
    {
        const int4* gB = (const int4*)Bp1;
        int4* lB = (int4*)sB;
#pragma unroll
        for (int i = 0; i < 2; ++i)
            lB[threadIdx.x + i * 256] = gB[threadIdx.x + i * 256];
    }
    __syncthreads();
    int wid = blockIdx.x * 4 + (threadIdx.x >> 6);
    if (wid >= NW) return;
    int lane = threadIdx.x & 63, m = lane & 15, quad = lane >> 4;
    int r0 = wid * 16;
    f32x4 acc[4];
#pragma unroll
    for (int t = 0; t < 4; ++t) acc[t] = (f32x4){0.f, 0.f, 0.f, 0.f};
    const bf16x8* bp = (const bf16x8*)sB;
#pragma unroll
    for (int s = 0; s < 2; ++s) {
        const float4* xp = (const float4*)(x + (size_t)(r0 + m) * 64 + s * 32 + quad * 8);
        float4 v0 = xp[0], v1 = xp[1];
        bf16x8 a;
        a[0] = (short)f2b(v0.x); a[1] = (short)f2b(v0.y);
        a[2] = (short)f2b(v0.z); a[3] = (short)f2b(v0.w);
        a[4] = (short)f2b(v1.x); a[5] = (short)f2b(v1.y);
        a[6] = (short)f2b(v1.z); a[7] = (short)f2b(v1.w);
#pragma unroll
        for (int t = 0; t < 4; ++t)
            acc[t] = __builtin_amdgcn_mfma_f32_16x16x32_bf16(
                a, bp[(s * 4 + t) * 64 + lane], acc[t], 0, 0, 0);
    }
#pragma unroll
    for (int reg = 0; reg < 4; ++reg) {
        int row = r0 + quad * 4 + reg;
        float di = dinv[row];
#pragma unroll
        for (int t = 0; t < 4; ++t)
            gbf[(size_t)row * 64 + t * 16 + m] = f2b(acc[t][reg] * di);
    }
}

// wave per node; 2 neighbors per step (lane>>5 = parity, lane&31 = col pair);
// unrolled 8 pairs deep to keep 8 gather loads in flight.
__global__ void __launch_bounds__(256) gather_finalize(
        const unsigned int* __restrict__ gbf_u, const int* __restrict__ csr,
        const int* __restrict__ row_start, const float* __restrict__ dinv,
        const float* __restrict__ b1, unsigned int* __restrict__ hbf_u, int N) {
    int wid = blockIdx.x * 4 + (threadIdx.x >> 6);
    if (wid >= N) return;
    int lane = threadIdx.x & 63;
    int which = lane >> 5, c2 = lane & 31;
    int base = row_start[wid];
    int deg = row_start[wid + 1] - base;
    float a0 = 0.f, a1 = 0.f;
    if (which == 0) {   // self loop row
        unsigned u = gbf_u[(size_t)wid * 32 + c2];
        a0 += __uint_as_float(u << 16);
        a1 += __uint_as_float(u & 0xffff0000u);
    }
    for (int j0 = 0; j0 < deg; j0 += 64) {
        int nidx = j0 + lane;
        int sidx = (nidx < deg) ? csr[base + nidx] : 0;
        int cnt = deg - j0; if (cnt > 64) cnt = 64;
        int full = cnt >> 1;
        int p = 0;
        for (; p + 8 <= full; p += 8) {
            unsigned u[8];
#pragma unroll
            for (int q = 0; q < 8; ++q) {
                int n = __shfl(sidx, (p + q) * 2 + which, 64);
                u[q] = gbf_u[(size_t)n * 32 + c2];
            }
#pragma unroll
            for (int q = 0; q < 8; ++q) {
                a0 += __uint_as_float(u[q] << 16);
                a1 += __uint_as_float(u[q] & 0xffff0000u);
            }
        }
        for (; p + 4 <= full; p += 4) {
            unsigned u[4];
#pragma unroll
            for (int q = 0; q < 4; ++q) {
                int n = __shfl(sidx, (p + q) * 2 + which, 64);
                u[q] = gbf_u[(size_t)n * 32 + c2];
            }
#pragma unroll
            for (int q = 0; q < 4; ++q) {
                a0 += __uint_as_float(u[q] << 16);
                a1 += __uint_as_float(u[q] & 0xffff0000u);
            }
        }
        for (; p < full; ++p) {
            int n = __shfl(sidx, p * 2 + which, 64);
            unsigned u = gbf_u[(size_t)n * 32 + c2];
            a0 += __uint_as_float(u << 16);
            a1 += __uint_as_float(u & 0xffff0000u);
        }
        if (cnt & 1) {
            int n = __shfl(sidx, cnt - 1, 64);
            if (which == 0) {
                unsigned u = gbf_u[(size_t)n * 32 + c2];
                a0 += __uint_as_float(u << 16);
                a1 += __uint_as_float(u & 0xffff0000u);
            }
        }
    }
    a0 += __shfl_xor(a0, 32, 64);
    a1 += __shfl_xor(a1, 32, 64);
    if (which == 0) {
        float di = dinv[wid];
        float h0 = di * a0 + b1[2 * c2];
        float h1 = di * a1 + b1[2 * c2 + 1];
        h0 = h0 > 0.f ? h0 : 0.f;
        h1 = h1 > 0.f ? h1 : 0.f;
        hbf_u[(size_t)wid * 32 + c2] = (unsigned)f2b(h0) | ((unsigned)f2b(h1) << 16);
    }
}

// One wave per 16 edges; K=160 (144 padded), 4 N-tiles. Pre-packed Bp staged
// via int4; all 5 A-frags loaded before the MFMA phase (sched_barrier).
__global__ void __launch_bounds__(256, 8) edge_mlp_mfma(
        const unsigned short* __restrict__ hbf, const float* __restrict__ ea,
        const int* __restrict__ src, const int* __restrict__ dst,
        const unsigned short* __restrict__ Bp,
        const float* __restrict__ bm1, const float* __restrict__ Wm2,
        const float* __restrict__ bm2, float* __restrict__ out, int E) {
    __shared__ unsigned short sB[5 * 4 * 64 * 8];   // 20 KB
    {
        const int4* gB = (const int4*)Bp;
        int4* lB = (int4*)sB;
#pragma unroll
        for (int i = 0; i < 5; ++i)
            lB[threadIdx.x + i * 256] = gB[threadIdx.x + i * 256];
    }
    __syncthreads();

    int lane = threadIdx.x & 63;
    int wave = threadIdx.x >> 6;
    int m = lane & 15, quad = lane >> 4;
    int e0 = (blockIdx.x * 4 + wave) * 16;
    if (e0 >= E) return;
    int e = e0 + m;
    int ec = e < E ? e : E - 1;
    int si = src[ec], di = dst[ec];

    // ---- load phase: all gathers in flight ----
    bf16x8 af[5];
    af[0] = *(const bf16x8*)(hbf + (size_t)si * 64 + quad * 8);
    af[1] = *(const bf16x8*)(hbf + (size_t)si * 64 + 32 + quad * 8);
    af[2] = *(const bf16x8*)(hbf + (size_t)di * 64 + quad * 8);
    af[3] = *(const bf16x8*)(hbf + (size_t)di * 64 + 32 + quad * 8);
    if (quad < 2) {
        const float4* ep = (const float4*)(ea + (size_t)ec * 16 + quad * 8);
        float4 v0 = ep[0], v1 = ep[1];
        af[4][0] = (short)f2b(v0.x); af[4][1] = (short)f2b(v0.y);
        af[4][2] = (short)f2b(v0.z); af[4][3] = (short)f2b(v0.w);
        af[4][4] = (short)f2b(v1.x); af[4][5] = (short)f2b(v1.y);
        af[4][6] = (short)f2b(v1.z); af[4][7] = (short)f2b(v1.w);
    } else {
#pragma unroll
        for (int j = 0; j < 8; ++j) af[4][j] = 0;
    }
    __builtin_amdgcn_sched_barrier(0);

    // ---- MFMA phase ----
    f32x4 acc[4];
#pragma unroll
    for (int t = 0; t < 4; ++t) acc[t] = (f32x4){0.f, 0.f, 0.f, 0.f};
    const bf16x8* bp = (const bf16x8*)sB;
#pragma unroll
    for (int s = 0; s < 5; ++s) {
#pragma unroll
        for (int t = 0; t < 4; ++t)
            acc[t] = __builtin_amdgcn_mfma_f32_16x16x32_bf16(
                af[s], bp[(s * 4 + t) * 64 + lane], acc[t], 0, 0, 0);
    }

    // epilogue: +bm1, relu, dot Wm2, reduce over 16 col-lanes, sigmoid
    float w2[4], bb[4];
#pragma unroll
    for (int t = 0; t < 4; ++t) {
        int col = t * 16 + m;
        bb[t] = bm1[col];
        w2[t] = Wm2[col];
    }
    float p[4];
#pragma unroll
    for (int r = 0; r < 4; ++r) {
        float sum = 0.0f;
#pragma unroll
        for (int t = 0; t < 4; ++t) {
            float hv = acc[t][r] + bb[t];
            sum += (hv > 0.0f ? hv : 0.0f) * w2[t];
        }
        p[r] = sum;
    }
#pragma unroll
    for (int off = 1; off < 16; off <<= 1) {
#pragma unroll
        for (int r = 0; r < 4; ++r) p[r] += __shfl_xor(p[r], off, 64);
    }
    float b2 = bm2[0];
    if (m < 4) {
        int eo = e0 + quad * 4 + m;
        if (eo < E) out[eo] = 1.0f / (1.0f + __expf(-(p[m] + b2)));
    }
}

extern "C" void kernel_launch(void* const* d_in, const int* in_sizes, int n_in,
                              void* d_out, int out_size, void* d_ws, size_t ws_size,
                              hipStream_t stream) {
    const float* x   = (const float*)d_in[0];
    const int*   src = (const int*)d_in[1];
    const int*   dst = (const int*)d_in[2];
    const float* ea  = (const float*)d_in[3];
    const float* W1  = (const float*)d_in[4];
    const float* b1  = (const float*)d_in[5];
    const float* Wm1 = (const float*)d_in[6];
    const float* bm1 = (const float*)d_in[7];
    const float* Wm2 = (const float*)d_in[8];
    const float* bm2 = (const float*)d_in[9];
    float* out = (float*)d_out;

    const int N = in_sizes[0] / 64;   // 50000
    const int E = in_sizes[1];        // 800000
    const int NB = (N + 255) / 256;   // 196 (<=256 required by scan23)
    const int NW = N / 16;            // 3125

    // ws layout (all chunks 256B-aligned):
    unsigned short* gbf = (unsigned short*)d_ws;            // N*64 bf16 (6.4 MB)
    unsigned short* hbf = gbf + (size_t)N * 64;             // N*64 bf16 (6.4 MB)
    int*   csr       = (int*)(hbf + (size_t)N * 64);        // E  (3.2 MB)
    int*   rank      = csr + E;                             // E  (3.2 MB)
    int*   cnt       = rank + E;                            // N
    int*   row_start = cnt + N;                             // N+1
    int*   bsum      = row_start + N + 2;                   // 256
    float* dinv      = (float*)(bsum + 256);                // N
    unsigned short* Bp  = (unsigned short*)(dinv + N);      // 10240
    unsigned short* Bp1 = Bp + 10240;                       // 4096

    hipMemsetAsync(cnt, 0, (size_t)N * sizeof(int), stream);
    pack_B<<<56, 256, 0, stream>>>(Wm1, W1, Bp, Bp1);
    hist<<<(E + 255) / 256, 256, 0, stream>>>(dst, cnt, rank, E);
    scan1<<<NB, 256, 0, stream>>>(cnt, row_start, bsum, N);
    scan23<<<NB, 256, 0, stream>>>(row_start, bsum, cnt, dinv, N, NB);
    fill<<<(E + 255) / 256, 256, 0, stream>>>(src, dst, rank, row_start, csr, E);
    node_gemm_mfma<<<(NW + 3) / 4, 256, 0, stream>>>(x, Bp1, dinv, gbf, NW);
    gather_finalize<<<(N + 3) / 4, 256, 0, stream>>>((const unsigned int*)gbf, csr,
                                                     row_start, dinv, b1,
                                                     (unsigned int*)hbf, N);
    edge_mlp_mfma<<<(E + 63) / 64, 256, 0, stream>>>(hbf, ea, src, dst, Bp,
                                                     bm1, Wm2, bm2, out, E);
}

// Round 9
// 226.353 us; speedup vs baseline: 1.4661x; 1.0252x over previous
//
#include <hip/hip_runtime.h>
#include <math.h>

// Problem constants: N=50000, E=800000, D=H=64, ED=16.
// Pipeline (CSR gather, bf16 g, atomic-free fill, PRE-PACKED weights):
//   cnt[i]=indeg, rank[e]=arrival order (ushort)  (hist)
//   row_start = exscan(cnt); dinv = rsqrt(cnt+1)  (scan1 + scan23)
//   csr[row_start[dst]+rank] = src (ushort)       (fused with node_gemm)
//   gbf = bf16((x @ W1) * dinv[row])              (fused gemm_fill, MFMA)
//   hbf[i] = bf16(relu(dinv[i]*(gbf[i] + sum gbf[s]) + b1))  (gather_finalize)
//   out[e] = sigmoid(relu([h_s|h_d|ea]@Wm1+bm1)@Wm2+bm2)     (edge_mlp_mfma)
//
// LESSONS ENCODED:
//  - hbf must NOT alias gbf (cross-block RW race, R2).
//  - Weight packing = separate tiny kernel + int4 LDS staging (R6: in-kernel
//    pack was 10k scalar loads/block, 3x regression).
//  - edge_mlp: 16 edges/wave; R4 vs R8 shows it's gather-THROUGHPUT bound
//    (32/wave @37% occ == 16/wave @72% occ), so no more ILP tuning there.
//  - csr/rank as ushort: src<50000<65536, rank<=indeg_max(~50). Halves fill's
//    random write-allocate; csr (1.6MB) fits per-XCD L2.

typedef __attribute__((ext_vector_type(8))) short bf16x8;
typedef __attribute__((ext_vector_type(4))) float f32x4;

__device__ __forceinline__ unsigned short f2b(float f) {
    unsigned u = __float_as_uint(f);
    unsigned r = (u + 0x7FFFu + ((u >> 16) & 1u)) >> 16;   // RNE
    return (unsigned short)r;
}

__global__ void hist(const int* __restrict__ dst, int* __restrict__ cnt,
                     unsigned short* __restrict__ rank, int E) {
    int e = blockIdx.x * blockDim.x + threadIdx.x;
    if (e < E) rank[e] = (unsigned short)atomicAdd(&cnt[dst[e]], 1);
}

__global__ void scan1(const int* __restrict__ cnt, int* __restrict__ part,
                      int* __restrict__ bsum, int N) {
    __shared__ int s[256];
    int tid = threadIdx.x;
    int i = blockIdx.x * 256 + tid;
    int v = (i < N) ? cnt[i] : 0;
    s[tid] = v;
    __syncthreads();
#pragma unroll
    for (int off = 1; off < 256; off <<= 1) {
        int t = (tid >= off) ? s[tid - off] : 0;
        __syncthreads();
        s[tid] += t;
        __syncthreads();
    }
    if (i < N) part[i] = s[tid] - v;
    if (tid == 255) bsum[blockIdx.x] = s[255];
}

// scan2+scan3 fused: every block redundantly scans bsum (nb<=256) in LDS.
__global__ void scan23(int* __restrict__ row_start, const int* __restrict__ bsum,
                       const int* __restrict__ cnt, float* __restrict__ dinv,
                       int N, int nb) {
    __shared__ int s[256];
    int tid = threadIdx.x;
    int v = (tid < nb) ? bsum[tid] : 0;
    s[tid] = v;
    __syncthreads();
#pragma unroll
    for (int off = 1; off < 256; off <<= 1) {
        int t = (tid >= off) ? s[tid - off] : 0;
        __syncthreads();
        s[tid] += t;
        __syncthreads();
    }
    int blkoff = (blockIdx.x > 0) ? s[blockIdx.x - 1] : 0;
    int i = blockIdx.x * 256 + tid;
    if (i >= N) return;
    int rs = row_start[i] + blkoff;
    row_start[i] = rs;
    dinv[i] = rsqrtf((float)cnt[i] + 1.0f);
    if (i == N - 1) row_start[N] = rs + cnt[i];
}

// Pack Wm1 [144x64] -> Bp (5 K-steps, K padded 160) and W1 [64x64] -> Bp1.
__global__ void pack_B(const float* __restrict__ Wm1, const float* __restrict__ W1,
                       unsigned short* __restrict__ Bp, unsigned short* __restrict__ Bp1) {
    int idx = blockIdx.x * blockDim.x + threadIdx.x;
    if (idx < 5 * 4 * 64 * 8) {
        int j = idx & 7, lane = (idx >> 3) & 63, t = (idx >> 9) & 3, s = idx >> 11;
        int k = s * 32 + (lane >> 4) * 8 + j, col = t * 16 + (lane & 15);
        float v = (k < 144) ? Wm1[k * 64 + col] : 0.0f;
        Bp[idx] = f2b(v);
    } else {
        int idx2 = idx - 5 * 4 * 64 * 8;
        if (idx2 < 2 * 4 * 64 * 8) {
            int j = idx2 & 7, lane = (idx2 >> 3) & 63, t = (idx2 >> 9) & 3, s = idx2 >> 11;
            int k = s * 32 + (lane >> 4) * 8 + j, col = t * 16 + (lane & 15);
            Bp1[idx2] = f2b(W1[k * 64 + col]);
        }
    }
}

// Fused: blocks [0,NGB) do the node GEMM; blocks [NGB,..) do the CSR fill.
// Both depend only on scan23 — fusing overlaps MFMA pipe with store pipe.
__global__ void __launch_bounds__(256) gemm_fill(
        const float* __restrict__ x, const unsigned short* __restrict__ Bp1,
        const float* __restrict__ dinv, unsigned short* __restrict__ gbf, int NW,
        const int* __restrict__ src, const int* __restrict__ dst,
        const unsigned short* __restrict__ rank, const int* __restrict__ row_start,
        unsigned short* __restrict__ csr, int E, int NGB) {
    if (blockIdx.x >= (unsigned)NGB) {
        // ---------------- fill branch (atomic-free) ----------------
        int e = (blockIdx.x - NGB) * blockDim.x + threadIdx.x;
        if (e < E) csr[row_start[dst[e]] + rank[e]] = (unsigned short)src[e];
        return;
    }
    // ---------------- node GEMM branch ----------------
    __shared__ unsigned short sB[2 * 4 * 64 * 8];   // 8 KB
    {
        const int4* gB = (const int4*)Bp1;
        int4* lB = (int4*)sB;
#pragma unroll
        for (int i = 0; i < 2; ++i)
            lB[threadIdx.x + i * 256] = gB[threadIdx.x + i * 256];
    }
    __syncthreads();
    int wid = blockIdx.x * 4 + (threadIdx.x >> 6);
    if (wid >= NW) return;
    int lane = threadIdx.x & 63, m = lane & 15, quad = lane >> 4;
    int r0 = wid * 16;
    f32x4 acc[4];
#pragma unroll
    for (int t = 0; t < 4; ++t) acc[t] = (f32x4){0.f, 0.f, 0.f, 0.f};
    const bf16x8* bp = (const bf16x8*)sB;
#pragma unroll
    for (int s = 0; s < 2; ++s) {
        const float4* xp = (const float4*)(x + (size_t)(r0 + m) * 64 + s * 32 + quad * 8);
        float4 v0 = xp[0], v1 = xp[1];
        bf16x8 a;
        a[0] = (short)f2b(v0.x); a[1] = (short)f2b(v0.y);
        a[2] = (short)f2b(v0.z); a[3] = (short)f2b(v0.w);
        a[4] = (short)f2b(v1.x); a[5] = (short)f2b(v1.y);
        a[6] = (short)f2b(v1.z); a[7] = (short)f2b(v1.w);
#pragma unroll
        for (int t = 0; t < 4; ++t)
            acc[t] = __builtin_amdgcn_mfma_f32_16x16x32_bf16(
                a, bp[(s * 4 + t) * 64 + lane], acc[t], 0, 0, 0);
    }
#pragma unroll
    for (int reg = 0; reg < 4; ++reg) {
        int row = r0 + quad * 4 + reg;
        float di = dinv[row];
#pragma unroll
        for (int t = 0; t < 4; ++t)
            gbf[(size_t)row * 64 + t * 16 + m] = f2b(acc[t][reg] * di);
    }
}

// wave per node; 2 neighbors per step (lane>>5 = parity, lane&31 = col pair);
// unrolled 8 pairs deep to keep 8 gather loads in flight. csr is ushort.
__global__ void __launch_bounds__(256) gather_finalize(
        const unsigned int* __restrict__ gbf_u, const unsigned short* __restrict__ csr,
        const int* __restrict__ row_start, const float* __restrict__ dinv,
        const float* __restrict__ b1, unsigned int* __restrict__ hbf_u, int N) {
    int wid = blockIdx.x * 4 + (threadIdx.x >> 6);
    if (wid >= N) return;
    int lane = threadIdx.x & 63;
    int which = lane >> 5, c2 = lane & 31;
    int base = row_start[wid];
    int deg = row_start[wid + 1] - base;
    float a0 = 0.f, a1 = 0.f;
    if (which == 0) {   // self loop row
        unsigned u = gbf_u[(size_t)wid * 32 + c2];
        a0 += __uint_as_float(u << 16);
        a1 += __uint_as_float(u & 0xffff0000u);
    }
    for (int j0 = 0; j0 < deg; j0 += 64) {
        int nidx = j0 + lane;
        int sidx = (nidx < deg) ? (int)csr[base + nidx] : 0;
        int cnt = deg - j0; if (cnt > 64) cnt = 64;
        int full = cnt >> 1;
        int p = 0;
        for (; p + 8 <= full; p += 8) {
            unsigned u[8];
#pragma unroll
            for (int q = 0; q < 8; ++q) {
                int n = __shfl(sidx, (p + q) * 2 + which, 64);
                u[q] = gbf_u[(size_t)n * 32 + c2];
            }
#pragma unroll
            for (int q = 0; q < 8; ++q) {
                a0 += __uint_as_float(u[q] << 16);
                a1 += __uint_as_float(u[q] & 0xffff0000u);
            }
        }
        for (; p + 4 <= full; p += 4) {
            unsigned u[4];
#pragma unroll
            for (int q = 0; q < 4; ++q) {
                int n = __shfl(sidx, (p + q) * 2 + which, 64);
                u[q] = gbf_u[(size_t)n * 32 + c2];
            }
#pragma unroll
            for (int q = 0; q < 4; ++q) {
                a0 += __uint_as_float(u[q] << 16);
                a1 += __uint_as_float(u[q] & 0xffff0000u);
            }
        }
        for (; p < full; ++p) {
            int n = __shfl(sidx, p * 2 + which, 64);
            unsigned u = gbf_u[(size_t)n * 32 + c2];
            a0 += __uint_as_float(u << 16);
            a1 += __uint_as_float(u & 0xffff0000u);
        }
        if (cnt & 1) {
            int n = __shfl(sidx, cnt - 1, 64);
            if (which == 0) {
                unsigned u = gbf_u[(size_t)n * 32 + c2];
                a0 += __uint_as_float(u << 16);
                a1 += __uint_as_float(u & 0xffff0000u);
            }
        }
    }
    a0 += __shfl_xor(a0, 32, 64);
    a1 += __shfl_xor(a1, 32, 64);
    if (which == 0) {
        float di = dinv[wid];
        float h0 = di * a0 + b1[2 * c2];
        float h1 = di * a1 + b1[2 * c2 + 1];
        h0 = h0 > 0.f ? h0 : 0.f;
        h1 = h1 > 0.f ? h1 : 0.f;
        hbf_u[(size_t)wid * 32 + c2] = (unsigned)f2b(h0) | ((unsigned)f2b(h1) << 16);
    }
}

// One wave per 16 edges; K=160 (144 padded), 4 N-tiles. Pre-packed Bp staged
// via int4; all 5 A-frags loaded before the MFMA phase (sched_barrier).
__global__ void __launch_bounds__(256, 8) edge_mlp_mfma(
        const unsigned short* __restrict__ hbf, const float* __restrict__ ea,
        const int* __restrict__ src, const int* __restrict__ dst,
        const unsigned short* __restrict__ Bp,
        const float* __restrict__ bm1, const float* __restrict__ Wm2,
        const float* __restrict__ bm2, float* __restrict__ out, int E) {
    __shared__ unsigned short sB[5 * 4 * 64 * 8];   // 20 KB
    {
        const int4* gB = (const int4*)Bp;
        int4* lB = (int4*)sB;
#pragma unroll
        for (int i = 0; i < 5; ++i)
            lB[threadIdx.x + i * 256] = gB[threadIdx.x + i * 256];
    }
    __syncthreads();

    int lane = threadIdx.x & 63;
    int wave = threadIdx.x >> 6;
    int m = lane & 15, quad = lane >> 4;
    int e0 = (blockIdx.x * 4 + wave) * 16;
    if (e0 >= E) return;
    int e = e0 + m;
    int ec = e < E ? e : E - 1;
    int si = src[ec], di = dst[ec];

    // ---- load phase: all gathers in flight ----
    bf16x8 af[5];
    af[0] = *(const bf16x8*)(hbf + (size_t)si * 64 + quad * 8);
    af[1] = *(const bf16x8*)(hbf + (size_t)si * 64 + 32 + quad * 8);
    af[2] = *(const bf16x8*)(hbf + (size_t)di * 64 + quad * 8);
    af[3] = *(const bf16x8*)(hbf + (size_t)di * 64 + 32 + quad * 8);
    if (quad < 2) {
        const float4* ep = (const float4*)(ea + (size_t)ec * 16 + quad * 8);
        float4 v0 = ep[0], v1 = ep[1];
        af[4][0] = (short)f2b(v0.x); af[4][1] = (short)f2b(v0.y);
        af[4][2] = (short)f2b(v0.z); af[4][3] = (short)f2b(v0.w);
        af[4][4] = (short)f2b(v1.x); af[4][5] = (short)f2b(v1.y);
        af[4][6] = (short)f2b(v1.z); af[4][7] = (short)f2b(v1.w);
    } else {
#pragma unroll
        for (int j = 0; j < 8; ++j) af[4][j] = 0;
    }
    __builtin_amdgcn_sched_barrier(0);

    // ---- MFMA phase ----
    f32x4 acc[4];
#pragma unroll
    for (int t = 0; t < 4; ++t) acc[t] = (f32x4){0.f, 0.f, 0.f, 0.f};
    const bf16x8* bp = (const bf16x8*)sB;
#pragma unroll
    for (int s = 0; s < 5; ++s) {
#pragma unroll
        for (int t = 0; t < 4; ++t)
            acc[t] = __builtin_amdgcn_mfma_f32_16x16x32_bf16(
                af[s], bp[(s * 4 + t) * 64 + lane], acc[t], 0, 0, 0);
    }

    // epilogue: +bm1, relu, dot Wm2, reduce over 16 col-lanes, sigmoid
    float w2[4], bb[4];
#pragma unroll
    for (int t = 0; t < 4; ++t) {
        int col = t * 16 + m;
        bb[t] = bm1[col];
        w2[t] = Wm2[col];
    }
    float p[4];
#pragma unroll
    for (int r = 0; r < 4; ++r) {
        float sum = 0.0f;
#pragma unroll
        for (int t = 0; t < 4; ++t) {
            float hv = acc[t][r] + bb[t];
            sum += (hv > 0.0f ? hv : 0.0f) * w2[t];
        }
        p[r] = sum;
    }
#pragma unroll
    for (int off = 1; off < 16; off <<= 1) {
#pragma unroll
        for (int r = 0; r < 4; ++r) p[r] += __shfl_xor(p[r], off, 64);
    }
    float b2 = bm2[0];
    if (m < 4) {
        int eo = e0 + quad * 4 + m;
        if (eo < E) out[eo] = 1.0f / (1.0f + __expf(-(p[m] + b2)));
    }
}

extern "C" void kernel_launch(void* const* d_in, const int* in_sizes, int n_in,
                              void* d_out, int out_size, void* d_ws, size_t ws_size,
                              hipStream_t stream) {
    const float* x   = (const float*)d_in[0];
    const int*   src = (const int*)d_in[1];
    const int*   dst = (const int*)d_in[2];
    const float* ea  = (const float*)d_in[3];
    const float* W1  = (const float*)d_in[4];
    const float* b1  = (const float*)d_in[5];
    const float* Wm1 = (const float*)d_in[6];
    const float* bm1 = (const float*)d_in[7];
    const float* Wm2 = (const float*)d_in[8];
    const float* bm2 = (const float*)d_in[9];
    float* out = (float*)d_out;

    const int N = in_sizes[0] / 64;   // 50000
    const int E = in_sizes[1];        // 800000
    const int NB = (N + 255) / 256;   // 196 (<=256 required by scan23)
    const int NW = N / 16;            // 3125
    const int NGB = (NW + 3) / 4;     // node-gemm blocks in fused kernel
    const int FB  = (E + 255) / 256;  // fill blocks

    // ws layout (all chunks 256B-aligned):
    unsigned short* gbf = (unsigned short*)d_ws;            // N*64 bf16 (6.4 MB)
    unsigned short* hbf = gbf + (size_t)N * 64;             // N*64 bf16 (6.4 MB)
    unsigned short* csr  = hbf + (size_t)N * 64;            // E ushort (1.6 MB)
    unsigned short* rank = csr + E;                         // E ushort (1.6 MB)
    int*   cnt       = (int*)(rank + E);                    // N
    int*   row_start = cnt + N;                             // N+1
    int*   bsum      = row_start + N + 2;                   // 256
    float* dinv      = (float*)(bsum + 256);                // N
    unsigned short* Bp  = (unsigned short*)(dinv + N);      // 10240
    unsigned short* Bp1 = Bp + 10240;                       // 4096

    hipMemsetAsync(cnt, 0, (size_t)N * sizeof(int), stream);
    pack_B<<<56, 256, 0, stream>>>(Wm1, W1, Bp, Bp1);
    hist<<<(E + 255) / 256, 256, 0, stream>>>(dst, cnt, rank, E);
    scan1<<<NB, 256, 0, stream>>>(cnt, row_start, bsum, N);
    scan23<<<NB, 256, 0, stream>>>(row_start, bsum, cnt, dinv, N, NB);
    gemm_fill<<<NGB + FB, 256, 0, stream>>>(x, Bp1, dinv, gbf, NW,
                                            src, dst, rank, row_start, csr, E, NGB);
    gather_finalize<<<(N + 3) / 4, 256, 0, stream>>>((const unsigned int*)gbf, csr,
                                                     row_start, dinv, b1,
                                                     (unsigned int*)hbf, N);
    edge_mlp_mfma<<<(E + 63) / 64, 256, 0, stream>>>(hbf, ea, src, dst, Bp,
                                                     bm1, Wm2, bm2, out, E);
}